// Round 1
// baseline (662.008 us; speedup 1.0000x reference)
//
#include <hip/hip_runtime.h>
#include <math.h>

#define N_NODES 12000
#define C 128
#define NEDGE 192000
#define BW 384  // u32 words per bitset row (12288 bits >= 12000)

// ---- build adjacency bitset: B[s] bit t set  (dedup == .at[].set(1.0)) ----
__global__ void build_adj(const int* __restrict__ ei, unsigned* __restrict__ B) {
    int e = blockIdx.x * blockDim.x + threadIdx.x;
    if (e >= NEDGE) return;
    int s = ei[e];
    int t = ei[NEDGE + e];
    atomicOr(&B[(size_t)s * BW + (t >> 5)], 1u << (t & 31));
}

// ---- agg1[src] += x[tgt], multiplicity preserved (segment_sum) ----
__global__ void scatter_agg1(const int* __restrict__ ei, const float* __restrict__ x,
                             float* __restrict__ agg1) {
    int gid = blockIdx.x * blockDim.x + threadIdx.x;
    int e = gid >> 7;   // /128
    int c = gid & 127;
    if (e >= NEDGE) return;
    int s = ei[e];
    int t = ei[NEDGE + e];
    atomicAdd(&agg1[(size_t)s * C + c], x[(size_t)t * C + c]);
}

// ---- fused: B2row = OR of neighbor bitrows; clear diag; agg2[i] = sum x[k] over set bits ----
__global__ __launch_bounds__(256) void twohop_agg2(const unsigned* __restrict__ B,
                                                   const float* __restrict__ x,
                                                   float* __restrict__ agg2) {
    __shared__ unsigned rowi[BW];
    __shared__ unsigned acc[BW];
    __shared__ int lst[2048];          // 64 words * 32 bits max per chunk
    __shared__ int cnt;
    __shared__ float xbuf[C];
    const int i = blockIdx.x;
    const int tid = threadIdx.x;

    for (int w = tid; w < BW; w += 256) {
        rowi[w] = B[(size_t)i * BW + w];
        acc[w] = 0u;
    }
    __syncthreads();

    // OR neighbor rows into acc. Each acc word owned by a fixed thread -> no races, no barriers.
    for (int w = 0; w < BW; ++w) {
        unsigned bits = rowi[w];               // broadcast read, uniform across threads
        while (bits) {
            int j = (w << 5) + __ffs(bits) - 1;
            bits &= bits - 1;
            const unsigned* Brow = &B[(size_t)j * BW];
            for (int ww = tid; ww < BW; ww += 256)
                acc[ww] |= Brow[ww];
        }
    }
    __syncthreads();
    if (tid == 0) acc[i >> 5] &= ~(1u << (i & 31));   // zero diagonal
    __syncthreads();

    // enumerate set bits in chunks of 64 words (<=2048 bits, fits lst), gather-sum x rows
    const int h = tid >> 7;       // 0/1: two 128-thread halves split the list
    const int c = tid & 127;
    float sum = 0.f;
    for (int base = 0; base < BW; base += 64) {
        if (tid == 0) cnt = 0;
        __syncthreads();
        if (tid < 64) {
            unsigned bits = acc[base + tid];
            while (bits) {
                int b = __ffs(bits) - 1;
                bits &= bits - 1;
                int pos = atomicAdd(&cnt, 1);
                lst[pos] = ((base + tid) << 5) + b;
            }
        }
        __syncthreads();
        const int n = cnt;
        for (int idx = h; idx < n; idx += 2) {
            int k = lst[idx];
            sum += x[(size_t)k * C + c];
        }
        __syncthreads();
    }
    if (h == 1) xbuf[c] = sum;
    __syncthreads();
    if (h == 0) agg2[(size_t)i * C + c] = sum + xbuf[c];
}

// ---- out = A @ W + bias   (A: rows x 128, W: 128 x 128) ----
__global__ __launch_bounds__(256) void gemm_bias(const float* __restrict__ A,
                                                 const float* __restrict__ W,
                                                 const float* __restrict__ bias,
                                                 float* __restrict__ out, int rows) {
    __shared__ float As[32][C];
    const int r0 = blockIdx.x * 32;
    const int tid = threadIdx.x;
    for (int idx = tid; idx < 32 * C; idx += 256) {
        int r = idx >> 7, k = idx & 127;
        As[r][k] = (r0 + r < rows) ? A[(size_t)(r0 + r) * C + k] : 0.f;
    }
    __syncthreads();
    const int c = tid & 127;
    const int rg = (tid >> 7) * 16;
    float accv[16];
#pragma unroll
    for (int r = 0; r < 16; ++r) accv[r] = 0.f;
    for (int k = 0; k < C; ++k) {
        float wv = W[(size_t)k * C + c];     // coalesced, L2-resident
#pragma unroll
        for (int r = 0; r < 16; ++r)
            accv[r] += As[rg + r][k] * wv;   // LDS broadcast read
    }
    const float bv = bias[c];
#pragma unroll
    for (int r = 0; r < 16; ++r) {
        int rr = r0 + rg + r;
        if (rr < rows) out[(size_t)rr * C + c] = accv[r] + bv;
    }
}

// ---- gate = sigmoid([z1,z2] @ Wg + bg); out = gate*z1 + (1-gate)*z2 ----
__global__ __launch_bounds__(256) void gate_out(const float* __restrict__ z1,
                                                const float* __restrict__ z2,
                                                const float* __restrict__ Wg,
                                                const float* __restrict__ bg,
                                                float* __restrict__ out) {
    __shared__ float s1[32][C];
    __shared__ float s2[32][C];
    const int r0 = blockIdx.x * 32;
    const int tid = threadIdx.x;
    for (int idx = tid; idx < 32 * C; idx += 256) {
        int r = idx >> 7, k = idx & 127;
        s1[r][k] = z1[(size_t)(r0 + r) * C + k];
        s2[r][k] = z2[(size_t)(r0 + r) * C + k];
    }
    __syncthreads();
    const int c = tid & 127;
    const int rg = (tid >> 7) * 16;
    float acc[16];
#pragma unroll
    for (int r = 0; r < 16; ++r) acc[r] = 0.f;
    for (int k = 0; k < C; ++k) {
        float wv = Wg[(size_t)k * C + c];
#pragma unroll
        for (int r = 0; r < 16; ++r) acc[r] += s1[rg + r][k] * wv;
    }
    for (int k = 0; k < C; ++k) {
        float wv = Wg[(size_t)(C + k) * C + c];
#pragma unroll
        for (int r = 0; r < 16; ++r) acc[r] += s2[rg + r][k] * wv;
    }
    const float bv = bg[c];
#pragma unroll
    for (int r = 0; r < 16; ++r) {
        float g = 1.f / (1.f + expf(-(acc[r] + bv)));
        float a = s1[rg + r][c];
        float b = s2[rg + r][c];
        out[(size_t)(r0 + rg + r) * C + c] = g * a + (1.f - g) * b;
    }
}

extern "C" void kernel_launch(void* const* d_in, const int* in_sizes, int n_in,
                              void* d_out, int out_size, void* d_ws, size_t ws_size,
                              hipStream_t stream) {
    const float* x  = (const float*)d_in[0];
    const int*   ei = (const int*)d_in[1];
    const float* W1 = (const float*)d_in[2];
    const float* b1 = (const float*)d_in[3];
    const float* W2 = (const float*)d_in[4];
    const float* b2 = (const float*)d_in[5];
    const float* Wg = (const float*)d_in[6];
    const float* bg = (const float*)d_in[7];
    float* out = (float*)d_out;

    char* ws = (char*)d_ws;
    unsigned* B = (unsigned*)ws;                          // N*BW u32 = 18.4 MB
    float* agg1 = (float*)(ws + (size_t)N_NODES * BW * 4);
    float* agg2 = agg1 + (size_t)N_NODES * C;
    float* z1   = agg2 + (size_t)N_NODES * C;
    float* z2   = z1   + (size_t)N_NODES * C;

    hipMemsetAsync(B, 0, (size_t)N_NODES * BW * sizeof(unsigned), stream);
    hipMemsetAsync(agg1, 0, (size_t)N_NODES * C * sizeof(float), stream);

    build_adj<<<(NEDGE + 255) / 256, 256, 0, stream>>>(ei, B);
    scatter_agg1<<<(NEDGE * C) / 256, 256, 0, stream>>>(ei, x, agg1);
    twohop_agg2<<<N_NODES, 256, 0, stream>>>(B, x, agg2);
    gemm_bias<<<N_NODES / 32, 256, 0, stream>>>(agg1, W1, b1, z1, N_NODES);
    gemm_bias<<<N_NODES / 32, 256, 0, stream>>>(agg2, W2, b2, z2, N_NODES);
    gate_out<<<N_NODES / 32, 256, 0, stream>>>(z1, z2, Wg, bg, out);
}

// Round 2
// 289.845 us; speedup vs baseline: 2.2840x; 2.2840x over previous
//
#include <hip/hip_runtime.h>
#include <math.h>

#define N_NODES 12000
#define C 128
#define NEDGE 192000
#define BW 384  // u32 words per bitset row (12288 bits >= 12000)

__device__ __forceinline__ float bflo(unsigned u) { return __uint_as_float(u << 16); }
__device__ __forceinline__ float bfhi(unsigned u) { return __uint_as_float(u & 0xffff0000u); }

// ---- build: adjacency bitset (dedup) + out-degree histogram ----
__global__ void build_graph(const int* __restrict__ ei, unsigned* __restrict__ B,
                            int* __restrict__ deg) {
    int e = blockIdx.x * blockDim.x + threadIdx.x;
    if (e >= NEDGE) return;
    int s = ei[e];
    int t = ei[NEDGE + e];
    atomicOr(&B[(size_t)s * BW + (t >> 5)], 1u << (t & 31));
    atomicAdd(&deg[s], 1);
}

// ---- exclusive scan of degrees -> CSR offsets (single block) ----
__global__ __launch_bounds__(256) void scan_offsets(const int* __restrict__ deg,
                                                    int* __restrict__ off) {
    __shared__ int s[256];
    const int t = threadIdx.x;
    const int PER = 47;  // 256*47 = 12032 >= 12000
    int lo = t * PER, hi = lo + PER;
    if (hi > N_NODES) hi = N_NODES;
    int sum = 0;
    for (int i = lo; i < hi; ++i) sum += deg[i];
    s[t] = sum;
    __syncthreads();
    for (int d = 1; d < 256; d <<= 1) {
        int v = (t >= d) ? s[t - d] : 0;
        __syncthreads();
        s[t] += v;
        __syncthreads();
    }
    int run = t ? s[t - 1] : 0;
    for (int i = lo; i < hi; ++i) { off[i] = run; run += deg[i]; }
    if (t == 255) off[N_NODES] = run;
}

// ---- fill CSR columns (order within row irrelevant; duplicates kept) ----
__global__ void fill_csr(const int* __restrict__ ei, const int* __restrict__ off,
                         int* __restrict__ cur, int* __restrict__ col) {
    int e = blockIdx.x * blockDim.x + threadIdx.x;
    if (e >= NEDGE) return;
    int s = ei[e];
    int t = ei[NEDGE + e];
    int pos = atomicAdd(&cur[s], 1);
    col[off[s] + pos] = t;
}

// ---- x (fp32) -> bf16 (round-to-nearest), packed pairs ----
__global__ void convert_x(const float* __restrict__ x, unsigned* __restrict__ xbu) {
    int g = blockIdx.x * blockDim.x + threadIdx.x;
    if (g >= N_NODES * C / 2) return;
    unsigned a = __float_as_uint(x[2 * g]);
    unsigned b = __float_as_uint(x[2 * g + 1]);
    unsigned ra = (a + 0x7fffu + ((a >> 16) & 1u)) >> 16;
    unsigned rb = (b + 0x7fffu + ((b >> 16) & 1u)) >> 16;
    xbu[g] = ra | (rb << 16);
}

// ---- fused: agg1 (CSR gather, multiplicity) + 2-hop OR + enumerate + agg2 gather ----
__global__ __launch_bounds__(256) void twohop_fused(const unsigned* __restrict__ B,
                                                    const int* __restrict__ off,
                                                    const int* __restrict__ col,
                                                    const float* __restrict__ x,
                                                    const unsigned* __restrict__ xb,
                                                    float* __restrict__ agg1,
                                                    float* __restrict__ agg2) {
    __shared__ unsigned acc[BW];    // 1.5 KB
    __shared__ int lst[4096];       // 16 KB (>= 128 words * 32 bits: cannot overflow)
    __shared__ float red[128][17];  // 8.7 KB, padded stride to spread banks
    __shared__ int wtot[2];
    const int i = blockIdx.x;
    const int tid = threadIdx.x;
    const int lane = tid & 63;
    const int wv = tid >> 6;
    const int rowbeg = off[i], rowend = off[i + 1];

    for (int w = tid; w < BW; w += 256) acc[w] = 0u;

    // ---- agg1: sum x[t] over CSR row (fp32, multiplicity preserved) ----
    {
        const int h = tid >> 7, c = tid & 127;
        float s1 = 0.f;
        for (int idx = rowbeg + h; idx < rowend; idx += 2)
            s1 += x[(size_t)col[idx] * C + c];
        float* redf = (float*)red;
        if (h == 1) redf[c] = s1;
        __syncthreads();  // also covers acc init
        if (h == 0) agg1[(size_t)i * C + c] = s1 + redf[c];
    }

    // ---- phase 1: OR neighbor bit-rows; per-wave register accumulation ----
    {
        unsigned r0 = 0, r1 = 0, r2 = 0, r3 = 0, r4 = 0, r5 = 0;
        for (int idx = rowbeg + wv; idx < rowend; idx += 4) {
            const unsigned* Bj = B + (size_t)col[idx] * BW;
            r0 |= Bj[lane];
            r1 |= Bj[lane + 64];
            r2 |= Bj[lane + 128];
            r3 |= Bj[lane + 192];
            r4 |= Bj[lane + 256];
            r5 |= Bj[lane + 320];
        }
        if (r0) atomicOr(&acc[lane], r0);
        if (r1) atomicOr(&acc[lane + 64], r1);
        if (r2) atomicOr(&acc[lane + 128], r2);
        if (r3) atomicOr(&acc[lane + 192], r3);
        if (r4) atomicOr(&acc[lane + 256], r4);
        if (r5) atomicOr(&acc[lane + 320], r5);
    }
    __syncthreads();
    if (tid == 0) acc[i >> 5] &= ~(1u << (i & 31));  // zero diagonal

    // ---- enumerate set bits (prefix-scan reservation) + gather bf16 x rows ----
    const int l16 = tid & 15, grp = tid >> 4;  // 16 lanes/row, 16 groups
    float a0 = 0.f, a1 = 0.f, a2 = 0.f, a3 = 0.f, a4 = 0.f, a5 = 0.f, a6 = 0.f, a7 = 0.f;
    for (int chunk = 0; chunk < 3; ++chunk) {
        __syncthreads();  // lst/wtot from previous chunk fully consumed; acc ready
        if (tid < 128) {
            unsigned v = acc[chunk * 128 + tid];
            int n = __popc(v);
            int p = n;
            for (int d = 1; d < 64; d <<= 1) {
                int u = __shfl_up(p, d);
                if (lane >= d) p += u;
            }
            if (lane == 63) wtot[wv] = p;
            __syncthreads();
            int o = ((wv == 1) ? wtot[0] : 0) + p - n;
            int wbase = (chunk * 128 + tid) << 5;
            while (v) {
                int b = __ffs(v) - 1;
                v &= v - 1;
                lst[o++] = wbase + b;
            }
        } else {
            __syncthreads();
        }
        __syncthreads();
        const int total = wtot[0] + wtot[1];
        for (int idx = grp; idx < total; idx += 16) {
            int k = lst[idx];
            const uint4* p4 = (const uint4*)xb + (size_t)k * 16 + l16;
            uint4 u = *p4;
            a0 += bflo(u.x); a1 += bfhi(u.x);
            a2 += bflo(u.y); a3 += bfhi(u.y);
            a4 += bflo(u.z); a5 += bfhi(u.z);
            a6 += bflo(u.w); a7 += bfhi(u.w);
        }
    }
    __syncthreads();
    red[l16 * 8 + 0][grp] = a0;
    red[l16 * 8 + 1][grp] = a1;
    red[l16 * 8 + 2][grp] = a2;
    red[l16 * 8 + 3][grp] = a3;
    red[l16 * 8 + 4][grp] = a4;
    red[l16 * 8 + 5][grp] = a5;
    red[l16 * 8 + 6][grp] = a6;
    red[l16 * 8 + 7][grp] = a7;
    __syncthreads();
    if (tid < 128) {
        float s = 0.f;
#pragma unroll
        for (int g = 0; g < 16; ++g) s += red[tid][g];
        agg2[(size_t)i * C + tid] = s;
    }
}

// ---- out = A @ W + bias   (A: rows x 128, W: 128 x 128) ----
__global__ __launch_bounds__(256) void gemm_bias(const float* __restrict__ A,
                                                 const float* __restrict__ W,
                                                 const float* __restrict__ bias,
                                                 float* __restrict__ out, int rows) {
    __shared__ float As[32][C];
    const int r0 = blockIdx.x * 32;
    const int tid = threadIdx.x;
    for (int idx = tid; idx < 32 * C; idx += 256) {
        int r = idx >> 7, k = idx & 127;
        As[r][k] = (r0 + r < rows) ? A[(size_t)(r0 + r) * C + k] : 0.f;
    }
    __syncthreads();
    const int c = tid & 127;
    const int rg = (tid >> 7) * 16;
    float accv[16];
#pragma unroll
    for (int r = 0; r < 16; ++r) accv[r] = 0.f;
    for (int k = 0; k < C; ++k) {
        float wv = W[(size_t)k * C + c];
#pragma unroll
        for (int r = 0; r < 16; ++r)
            accv[r] += As[rg + r][k] * wv;
    }
    const float bv = bias[c];
#pragma unroll
    for (int r = 0; r < 16; ++r) {
        int rr = r0 + rg + r;
        if (rr < rows) out[(size_t)rr * C + c] = accv[r] + bv;
    }
}

// ---- gate = sigmoid([z1,z2] @ Wg + bg); out = gate*z1 + (1-gate)*z2 ----
__global__ __launch_bounds__(256) void gate_out(const float* __restrict__ z1,
                                                const float* __restrict__ z2,
                                                const float* __restrict__ Wg,
                                                const float* __restrict__ bg,
                                                float* __restrict__ out) {
    __shared__ float s1[32][C];
    __shared__ float s2[32][C];
    const int r0 = blockIdx.x * 32;
    const int tid = threadIdx.x;
    for (int idx = tid; idx < 32 * C; idx += 256) {
        int r = idx >> 7, k = idx & 127;
        s1[r][k] = z1[(size_t)(r0 + r) * C + k];
        s2[r][k] = z2[(size_t)(r0 + r) * C + k];
    }
    __syncthreads();
    const int c = tid & 127;
    const int rg = (tid >> 7) * 16;
    float acc[16];
#pragma unroll
    for (int r = 0; r < 16; ++r) acc[r] = 0.f;
    for (int k = 0; k < C; ++k) {
        float wv = Wg[(size_t)k * C + c];
#pragma unroll
        for (int r = 0; r < 16; ++r) acc[r] += s1[rg + r][k] * wv;
    }
    for (int k = 0; k < C; ++k) {
        float wv = Wg[(size_t)(C + k) * C + c];
#pragma unroll
        for (int r = 0; r < 16; ++r) acc[r] += s2[rg + r][k] * wv;
    }
    const float bv = bg[c];
#pragma unroll
    for (int r = 0; r < 16; ++r) {
        float g = 1.f / (1.f + expf(-(acc[r] + bv)));
        float a = s1[rg + r][c];
        float b = s2[rg + r][c];
        out[(size_t)(r0 + rg + r) * C + c] = g * a + (1.f - g) * b;
    }
}

extern "C" void kernel_launch(void* const* d_in, const int* in_sizes, int n_in,
                              void* d_out, int out_size, void* d_ws, size_t ws_size,
                              hipStream_t stream) {
    const float* x  = (const float*)d_in[0];
    const int*   ei = (const int*)d_in[1];
    const float* W1 = (const float*)d_in[2];
    const float* b1 = (const float*)d_in[3];
    const float* W2 = (const float*)d_in[4];
    const float* b2 = (const float*)d_in[5];
    const float* Wg = (const float*)d_in[6];
    const float* bg = (const float*)d_in[7];
    float* out = (float*)d_out;

    char* ws = (char*)d_ws;
    size_t o = 0;
    auto alloc = [&](size_t bytes) { char* p = ws + o; o = (o + bytes + 255) & ~(size_t)255; return p; };
    unsigned* B   = (unsigned*)alloc((size_t)N_NODES * BW * 4);   // 18.4 MB
    int* col      = (int*)alloc((size_t)NEDGE * 4);
    int* deg      = (int*)alloc((size_t)N_NODES * 4);
    int* off      = (int*)alloc((size_t)(N_NODES + 1) * 4);
    int* cur      = (int*)alloc((size_t)N_NODES * 4);
    unsigned* xb  = (unsigned*)alloc((size_t)N_NODES * C * 2);    // bf16 x
    float* agg1   = (float*)alloc((size_t)N_NODES * C * 4);
    float* agg2   = (float*)alloc((size_t)N_NODES * C * 4);
    // z1/z2 alias the B bitset region (dead after twohop_fused; stream-ordered)
    float* z1 = (float*)B;
    float* z2 = (float*)(B + (size_t)N_NODES * BW / 2);

    hipMemsetAsync(B, 0, (size_t)N_NODES * BW * 4, stream);
    hipMemsetAsync(deg, 0, (size_t)N_NODES * 4, stream);
    hipMemsetAsync(cur, 0, (size_t)N_NODES * 4, stream);

    build_graph<<<(NEDGE + 255) / 256, 256, 0, stream>>>(ei, B, deg);
    scan_offsets<<<1, 256, 0, stream>>>(deg, off);
    fill_csr<<<(NEDGE + 255) / 256, 256, 0, stream>>>(ei, off, cur, col);
    convert_x<<<(N_NODES * C / 2 + 255) / 256, 256, 0, stream>>>(x, xb);
    twohop_fused<<<N_NODES, 256, 0, stream>>>(B, off, col, x, xb, agg1, agg2);
    gemm_bias<<<N_NODES / 32, 256, 0, stream>>>(agg1, W1, b1, z1, N_NODES);
    gemm_bias<<<N_NODES / 32, 256, 0, stream>>>(agg2, W2, b2, z2, N_NODES);
    gate_out<<<N_NODES / 32, 256, 0, stream>>>(z1, z2, Wg, bg, out);
}

// Round 3
// 272.866 us; speedup vs baseline: 2.4261x; 1.0622x over previous
//
#include <hip/hip_runtime.h>
#include <math.h>

#define N_NODES 12000
#define C 128
#define NEDGE 192000
#define BW 384  // u32 words per LDS dedup bitset (12288 bits >= 12000)

__device__ __forceinline__ float bflo(unsigned u) { return __uint_as_float(u << 16); }
__device__ __forceinline__ float bfhi(unsigned u) { return __uint_as_float(u & 0xffff0000u); }

// ---- out-degree histogram ----
__global__ void degree_hist(const int* __restrict__ ei, int* __restrict__ deg) {
    int e = blockIdx.x * blockDim.x + threadIdx.x;
    if (e >= NEDGE) return;
    atomicAdd(&deg[ei[e]], 1);
}

// ---- exclusive scan of degrees -> CSR offsets (single block) ----
__global__ __launch_bounds__(256) void scan_offsets(const int* __restrict__ deg,
                                                    int* __restrict__ off) {
    __shared__ int s[256];
    const int t = threadIdx.x;
    const int PER = 47;  // 256*47 = 12032 >= 12000
    int lo = t * PER, hi = lo + PER;
    if (hi > N_NODES) hi = N_NODES;
    int sum = 0;
    for (int i = lo; i < hi; ++i) sum += deg[i];
    s[t] = sum;
    __syncthreads();
    for (int d = 1; d < 256; d <<= 1) {
        int v = (t >= d) ? s[t - d] : 0;
        __syncthreads();
        s[t] += v;
        __syncthreads();
    }
    int run = t ? s[t - 1] : 0;
    for (int i = lo; i < hi; ++i) { off[i] = run; run += deg[i]; }
    if (t == 255) off[N_NODES] = run;
}

// ---- fill CSR columns (order within row irrelevant; duplicates kept) ----
__global__ void fill_csr(const int* __restrict__ ei, const int* __restrict__ off,
                         int* __restrict__ cur, int* __restrict__ col) {
    int e = blockIdx.x * blockDim.x + threadIdx.x;
    if (e >= NEDGE) return;
    int s = ei[e];
    int t = ei[NEDGE + e];
    int pos = atomicAdd(&cur[s], 1);
    col[off[s] + pos] = t;
}

// ---- x (fp32) -> bf16 (round-to-nearest), packed pairs ----
__global__ void convert_x(const float* __restrict__ x, unsigned* __restrict__ xbu) {
    int g = blockIdx.x * blockDim.x + threadIdx.x;
    if (g >= N_NODES * C / 2) return;
    unsigned a = __float_as_uint(x[2 * g]);
    unsigned b = __float_as_uint(x[2 * g + 1]);
    unsigned ra = (a + 0x7fffu + ((a >> 16) & 1u)) >> 16;
    unsigned rb = (b + 0x7fffu + ((b >> 16) & 1u)) >> 16;
    xbu[g] = ra | (rb << 16);
}

// ---- fused: agg1 (CSR gather) + 2-hop dedup via LDS bitset + enumerate + agg2 gather ----
__global__ __launch_bounds__(256) void twohop_fused(const int* __restrict__ off,
                                                    const int* __restrict__ col,
                                                    const float* __restrict__ x,
                                                    const unsigned* __restrict__ xb,
                                                    float* __restrict__ agg1,
                                                    float* __restrict__ agg2) {
    __shared__ unsigned acc[BW];    // 1.5 KB dedup bitset
    __shared__ int lst[4096];       // 16 KB (128 words * 32 bits: cannot overflow)
    __shared__ float red[128][17];  // 8.7 KB
    __shared__ int wtot[2];
    const int i = blockIdx.x;
    const int tid = threadIdx.x;
    const int lane = tid & 63;
    const int wv = tid >> 6;
    const int rowbeg = off[i], rowend = off[i + 1];

    for (int w = tid; w < BW; w += 256) acc[w] = 0u;
    __syncthreads();

    // ---- 2-hop union: for each neighbor j, set bits of j's adjacency list ----
    for (int idx = rowbeg + wv; idx < rowend; idx += 4) {
        int j = col[idx];
        int jb = off[j], je = off[j + 1];
        for (int p = jb + lane; p < je; p += 64) {
            int t = col[p];
            atomicOr(&acc[t >> 5], 1u << (t & 31));
        }
    }

    // ---- agg1: sum x[t] over CSR row (fp32, multiplicity preserved) ----
    {
        const int h = tid >> 7, c = tid & 127;
        float s1 = 0.f;
        for (int idx = rowbeg + h; idx < rowend; idx += 2)
            s1 += x[(size_t)col[idx] * C + c];
        float* redf = (float*)red;
        if (h == 1) redf[c] = s1;
        __syncthreads();  // dedup atomics done + redf ready
        if (h == 0) agg1[(size_t)i * C + c] = s1 + redf[c];
    }
    if (tid == 0) acc[i >> 5] &= ~(1u << (i & 31));  // zero diagonal

    // ---- enumerate set bits (prefix-scan reservation) + gather bf16 x rows ----
    const int l16 = tid & 15, grp = tid >> 4;  // 16 lanes/row, 16 groups
    float a0 = 0.f, a1 = 0.f, a2 = 0.f, a3 = 0.f, a4 = 0.f, a5 = 0.f, a6 = 0.f, a7 = 0.f;
    for (int chunk = 0; chunk < 3; ++chunk) {
        __syncthreads();  // diag clear visible / lst from previous chunk consumed
        if (tid < 128) {
            unsigned v = acc[chunk * 128 + tid];
            int n = __popc(v);
            int p = n;
            for (int d = 1; d < 64; d <<= 1) {
                int u = __shfl_up(p, d);
                if (lane >= d) p += u;
            }
            if (lane == 63) wtot[wv] = p;
            __syncthreads();
            int o = ((wv == 1) ? wtot[0] : 0) + p - n;
            int wbase = (chunk * 128 + tid) << 5;
            while (v) {
                int b = __ffs(v) - 1;
                v &= v - 1;
                lst[o++] = wbase + b;
            }
        } else {
            __syncthreads();
        }
        __syncthreads();
        const int total = wtot[0] + wtot[1];
        for (int idx = grp; idx < total; idx += 16) {
            int k = lst[idx];
            const uint4* p4 = (const uint4*)xb + (size_t)k * 16 + l16;
            uint4 u = *p4;
            a0 += bflo(u.x); a1 += bfhi(u.x);
            a2 += bflo(u.y); a3 += bfhi(u.y);
            a4 += bflo(u.z); a5 += bfhi(u.z);
            a6 += bflo(u.w); a7 += bfhi(u.w);
        }
    }
    __syncthreads();
    red[l16 * 8 + 0][grp] = a0;
    red[l16 * 8 + 1][grp] = a1;
    red[l16 * 8 + 2][grp] = a2;
    red[l16 * 8 + 3][grp] = a3;
    red[l16 * 8 + 4][grp] = a4;
    red[l16 * 8 + 5][grp] = a5;
    red[l16 * 8 + 6][grp] = a6;
    red[l16 * 8 + 7][grp] = a7;
    __syncthreads();
    if (tid < 128) {
        float s = 0.f;
#pragma unroll
        for (int g = 0; g < 16; ++g) s += red[tid][g];
        agg2[(size_t)i * C + tid] = s;
    }
}

// ---- fused epilogue: z1 = agg1@W1+b1, z2 = agg2@W2+b2, gate, combine ----
__global__ __launch_bounds__(256) void epilogue(const float* __restrict__ agg1,
                                                const float* __restrict__ agg2,
                                                const float* __restrict__ W1,
                                                const float* __restrict__ b1,
                                                const float* __restrict__ W2,
                                                const float* __restrict__ b2,
                                                const float* __restrict__ Wg,
                                                const float* __restrict__ bg,
                                                float* __restrict__ out) {
    __shared__ float sA[32][C];  // agg1 tile, then z1 tile
    __shared__ float sB[32][C];  // agg2 tile, then z2 tile
    const int r0 = blockIdx.x * 32;
    const int tid = threadIdx.x;
    const int c = tid & 127;
    const int rg = (tid >> 7) * 16;

    for (int idx = tid; idx < 32 * C; idx += 256) {
        int r = idx >> 7, k = idx & 127;
        sA[r][k] = agg1[(size_t)(r0 + r) * C + k];
        sB[r][k] = agg2[(size_t)(r0 + r) * C + k];
    }
    __syncthreads();

    float z1v[16], z2v[16];
#pragma unroll
    for (int r = 0; r < 16; ++r) { z1v[r] = 0.f; z2v[r] = 0.f; }
    for (int k = 0; k < C; k += 4) {
        float w10 = W1[(size_t)(k + 0) * C + c], w11 = W1[(size_t)(k + 1) * C + c];
        float w12 = W1[(size_t)(k + 2) * C + c], w13 = W1[(size_t)(k + 3) * C + c];
        float w20 = W2[(size_t)(k + 0) * C + c], w21 = W2[(size_t)(k + 1) * C + c];
        float w22 = W2[(size_t)(k + 2) * C + c], w23 = W2[(size_t)(k + 3) * C + c];
#pragma unroll
        for (int r = 0; r < 16; ++r) {
            float4 a = *(const float4*)&sA[rg + r][k];
            float4 b = *(const float4*)&sB[rg + r][k];
            z1v[r] += a.x * w10 + a.y * w11 + a.z * w12 + a.w * w13;
            z2v[r] += b.x * w20 + b.y * w21 + b.z * w22 + b.w * w23;
        }
    }
    const float b1v = b1[c], b2v = b2[c];
#pragma unroll
    for (int r = 0; r < 16; ++r) { z1v[r] += b1v; z2v[r] += b2v; }
    __syncthreads();  // all reads of agg tiles done
#pragma unroll
    for (int r = 0; r < 16; ++r) { sA[rg + r][c] = z1v[r]; sB[rg + r][c] = z2v[r]; }
    __syncthreads();

    float gacc[16];
#pragma unroll
    for (int r = 0; r < 16; ++r) gacc[r] = 0.f;
    for (int k = 0; k < C; k += 4) {
        float g10 = Wg[(size_t)(k + 0) * C + c], g11 = Wg[(size_t)(k + 1) * C + c];
        float g12 = Wg[(size_t)(k + 2) * C + c], g13 = Wg[(size_t)(k + 3) * C + c];
        float g20 = Wg[(size_t)(C + k + 0) * C + c], g21 = Wg[(size_t)(C + k + 1) * C + c];
        float g22 = Wg[(size_t)(C + k + 2) * C + c], g23 = Wg[(size_t)(C + k + 3) * C + c];
#pragma unroll
        for (int r = 0; r < 16; ++r) {
            float4 a = *(const float4*)&sA[rg + r][k];
            float4 b = *(const float4*)&sB[rg + r][k];
            gacc[r] += a.x * g10 + a.y * g11 + a.z * g12 + a.w * g13
                     + b.x * g20 + b.y * g21 + b.z * g22 + b.w * g23;
        }
    }
    const float bgv = bg[c];
#pragma unroll
    for (int r = 0; r < 16; ++r) {
        float g = 1.f / (1.f + expf(-(gacc[r] + bgv)));
        out[(size_t)(r0 + rg + r) * C + c] = g * z1v[r] + (1.f - g) * z2v[r];
    }
}

extern "C" void kernel_launch(void* const* d_in, const int* in_sizes, int n_in,
                              void* d_out, int out_size, void* d_ws, size_t ws_size,
                              hipStream_t stream) {
    const float* x  = (const float*)d_in[0];
    const int*   ei = (const int*)d_in[1];
    const float* W1 = (const float*)d_in[2];
    const float* b1 = (const float*)d_in[3];
    const float* W2 = (const float*)d_in[4];
    const float* b2 = (const float*)d_in[5];
    const float* Wg = (const float*)d_in[6];
    const float* bg = (const float*)d_in[7];
    float* out = (float*)d_out;

    char* ws = (char*)d_ws;
    size_t o = 0;
    auto alloc = [&](size_t bytes) { char* p = ws + o; o = (o + bytes + 255) & ~(size_t)255; return p; };
    int* col      = (int*)alloc((size_t)NEDGE * 4);
    int* deg      = (int*)alloc((size_t)N_NODES * 4);
    int* off      = (int*)alloc((size_t)(N_NODES + 1) * 4);
    int* cur      = (int*)alloc((size_t)N_NODES * 4);
    unsigned* xb  = (unsigned*)alloc((size_t)N_NODES * C * 2);    // bf16 x
    float* agg1   = (float*)alloc((size_t)N_NODES * C * 4);
    float* agg2   = (float*)alloc((size_t)N_NODES * C * 4);

    hipMemsetAsync(deg, 0, (size_t)N_NODES * 4, stream);
    hipMemsetAsync(cur, 0, (size_t)N_NODES * 4, stream);

    degree_hist<<<(NEDGE + 255) / 256, 256, 0, stream>>>(ei, deg);
    scan_offsets<<<1, 256, 0, stream>>>(deg, off);
    fill_csr<<<(NEDGE + 255) / 256, 256, 0, stream>>>(ei, off, cur, col);
    convert_x<<<(N_NODES * C / 2 + 255) / 256, 256, 0, stream>>>(x, xb);
    twohop_fused<<<N_NODES, 256, 0, stream>>>(off, col, x, xb, agg1, agg2);
    epilogue<<<N_NODES / 32, 256, 0, stream>>>(agg1, agg2, W1, b1, W2, b2, Wg, bg, out);
}

// Round 4
// 210.391 us; speedup vs baseline: 3.1466x; 1.2969x over previous
//
#include <hip/hip_runtime.h>
#include <math.h>

#define N_NODES 12000
#define C 128
#define NEDGE 192000
#define BW 384  // u32 words per LDS dedup bitset (12288 bits >= 12000)

__device__ __forceinline__ float bflo(unsigned u) { return __uint_as_float(u << 16); }
__device__ __forceinline__ float bfhi(unsigned u) { return __uint_as_float(u & 0xffff0000u); }

// ---- fused: x (fp32) -> bf16 packed pairs  +  out-degree histogram ----
__global__ void prep(const float* __restrict__ x, unsigned* __restrict__ xbu,
                     const int* __restrict__ ei, int* __restrict__ deg) {
    int g = blockIdx.x * blockDim.x + threadIdx.x;
    if (g < N_NODES * C / 2) {
        unsigned a = __float_as_uint(x[2 * g]);
        unsigned b = __float_as_uint(x[2 * g + 1]);
        unsigned ra = (a + 0x7fffu + ((a >> 16) & 1u)) >> 16;
        unsigned rb = (b + 0x7fffu + ((b >> 16) & 1u)) >> 16;
        xbu[g] = ra | (rb << 16);
    }
    if (g < NEDGE) atomicAdd(&deg[ei[g]], 1);
}

// ---- exclusive scan of degrees -> CSR offsets (single 1024-thread block) ----
__global__ __launch_bounds__(1024) void scan_offsets(const int* __restrict__ deg,
                                                     int* __restrict__ off) {
    __shared__ int wsum[16];
    const int t = threadIdx.x;
    const int lane = t & 63, wv = t >> 6;
    const int PER = 12;  // 1024*12 = 12288 >= 12000
    const int lo = t * PER;
    int local[PER];
    int sum = 0;
#pragma unroll
    for (int k = 0; k < PER; ++k) {
        int i = lo + k;
        int d = (i < N_NODES) ? deg[i] : 0;
        local[k] = sum;
        sum += d;
    }
    int p = sum;
    for (int d = 1; d < 64; d <<= 1) {
        int u = __shfl_up(p, d);
        if (lane >= d) p += u;
    }
    if (lane == 63) wsum[wv] = p;
    __syncthreads();
    int wbase = 0;
    for (int k = 0; k < wv; ++k) wbase += wsum[k];
    const int tbase = wbase + p - sum;
#pragma unroll
    for (int k = 0; k < PER; ++k) {
        int i = lo + k;
        if (i < N_NODES) off[i] = tbase + local[k];
    }
    if (t == 0) off[N_NODES] = NEDGE;
}

// ---- fill CSR columns (order within row irrelevant; duplicates kept) ----
__global__ void fill_csr(const int* __restrict__ ei, const int* __restrict__ off,
                         int* __restrict__ cur, int* __restrict__ col) {
    int e = blockIdx.x * blockDim.x + threadIdx.x;
    if (e >= NEDGE) return;
    int s = ei[e];
    int t = ei[NEDGE + e];
    int pos = atomicAdd(&cur[s], 1);
    col[off[s] + pos] = t;
}

// ---- fused: agg1 (bf16 CSR gather) + flattened 2-hop union + bitset gather ----
__global__ __launch_bounds__(256) void twohop_fused(const int* __restrict__ off,
                                                    const int* __restrict__ col,
                                                    const unsigned* __restrict__ xb,
                                                    float* __restrict__ agg1,
                                                    float* __restrict__ agg2) {
    __shared__ unsigned acc[BW];    // 1.5 KB dedup bitset
    __shared__ int sjb[64];
    __shared__ int spos[64];
    __shared__ int stot;
    __shared__ float red[128][17];  // 8.7 KB
    const int i = blockIdx.x;
    const int tid = threadIdx.x;
    const int lane = tid & 63;
    const int grp = tid >> 4, l16 = tid & 15;
    const int rowbeg = off[i], rowend = off[i + 1];

    for (int w = tid; w < BW; w += 256) acc[w] = 0u;
    __syncthreads();  // acc ready for atomics

    // ---- 2-hop union, flattened: candidates of this 64-neighbor chunk ----
    for (int base = rowbeg; base < rowend; base += 64) {
        int d = rowend - base;
        if (d > 64) d = 64;
        if (tid < 64) {
            int len = 0;
            if (tid < d) {
                int j = col[base + tid];
                int jb = off[j];
                len = off[j + 1] - jb;
                sjb[tid] = jb;
            }
            int p = len;
            for (int dd = 1; dd < 64; dd <<= 1) {
                int u = __shfl_up(p, dd);
                if (lane >= dd) p += u;
            }
            spos[tid] = p - len;  // exclusive
            if (tid == 63) stot = p;
        }
        __syncthreads();
        const int total = stot;
        for (int q = tid; q < total; q += 256) {
            int lo = 0, hi = d - 1;  // largest k with spos[k] <= q
            while (lo < hi) {
                int mid = (lo + hi + 1) >> 1;
                if (spos[mid] <= q) lo = mid; else hi = mid - 1;
            }
            int t = col[sjb[lo] + (q - spos[lo])];
            atomicOr(&acc[t >> 5], 1u << (t & 31));
        }
        __syncthreads();
    }

    // ---- agg1: bf16 gather over own row (multiplicity preserved) ----
    float b0 = 0, b1 = 0, b2 = 0, b3 = 0, b4 = 0, b5 = 0, b6 = 0, b7 = 0;
    for (int idx = rowbeg + grp; idx < rowend; idx += 16) {
        int k = col[idx];
        uint4 u = *((const uint4*)xb + (size_t)k * 16 + l16);
        b0 += bflo(u.x); b1 += bfhi(u.x);
        b2 += bflo(u.y); b3 += bfhi(u.y);
        b4 += bflo(u.z); b5 += bfhi(u.z);
        b6 += bflo(u.w); b7 += bfhi(u.w);
    }

    if (tid == 0) acc[i >> 5] &= ~(1u << (i & 31));  // zero diagonal (acc quiet since loop sync)
    __syncthreads();

    // ---- agg2: gather directly from bitset; group g owns words g, g+16, ... ----
    float a0 = 0, a1 = 0, a2 = 0, a3 = 0, a4 = 0, a5 = 0, a6 = 0, a7 = 0;
#pragma unroll 4
    for (int it = 0; it < BW / 16; ++it) {
        const int w = grp + (it << 4);
        unsigned v = acc[w];
        const int wbase = w << 5;
        while (v) {
            int b = __ffs(v) - 1;
            v &= v - 1;
            uint4 u = *((const uint4*)xb + (size_t)(wbase + b) * 16 + l16);
            a0 += bflo(u.x); a1 += bfhi(u.x);
            a2 += bflo(u.y); a3 += bfhi(u.y);
            a4 += bflo(u.z); a5 += bfhi(u.z);
            a6 += bflo(u.w); a7 += bfhi(u.w);
        }
    }

    // ---- cross-group reductions: agg2 then agg1 ----
    __syncthreads();
    red[l16 * 8 + 0][grp] = a0; red[l16 * 8 + 1][grp] = a1;
    red[l16 * 8 + 2][grp] = a2; red[l16 * 8 + 3][grp] = a3;
    red[l16 * 8 + 4][grp] = a4; red[l16 * 8 + 5][grp] = a5;
    red[l16 * 8 + 6][grp] = a6; red[l16 * 8 + 7][grp] = a7;
    __syncthreads();
    if (tid < 128) {
        float s = 0.f;
#pragma unroll
        for (int g = 0; g < 16; ++g) s += red[tid][g];
        agg2[(size_t)i * C + tid] = s;
    }
    __syncthreads();
    red[l16 * 8 + 0][grp] = b0; red[l16 * 8 + 1][grp] = b1;
    red[l16 * 8 + 2][grp] = b2; red[l16 * 8 + 3][grp] = b3;
    red[l16 * 8 + 4][grp] = b4; red[l16 * 8 + 5][grp] = b5;
    red[l16 * 8 + 6][grp] = b6; red[l16 * 8 + 7][grp] = b7;
    __syncthreads();
    if (tid < 128) {
        float s = 0.f;
#pragma unroll
        for (int g = 0; g < 16; ++g) s += red[tid][g];
        agg1[(size_t)i * C + tid] = s;
    }
}

// ---- fused epilogue: z1 = agg1@W1+b1, z2 = agg2@W2+b2, gate, combine ----
__global__ __launch_bounds__(256) void epilogue(const float* __restrict__ agg1,
                                                const float* __restrict__ agg2,
                                                const float* __restrict__ W1,
                                                const float* __restrict__ b1,
                                                const float* __restrict__ W2,
                                                const float* __restrict__ b2,
                                                const float* __restrict__ Wg,
                                                const float* __restrict__ bg,
                                                float* __restrict__ out) {
    __shared__ float sA[32][C];  // agg1 tile, then z1 tile
    __shared__ float sB[32][C];  // agg2 tile, then z2 tile
    const int r0 = blockIdx.x * 32;
    const int tid = threadIdx.x;
    const int c = tid & 127;
    const int rg = (tid >> 7) * 16;

    for (int idx = tid; idx < 32 * C; idx += 256) {
        int r = idx >> 7, k = idx & 127;
        sA[r][k] = agg1[(size_t)(r0 + r) * C + k];
        sB[r][k] = agg2[(size_t)(r0 + r) * C + k];
    }
    __syncthreads();

    float z1v[16], z2v[16];
#pragma unroll
    for (int r = 0; r < 16; ++r) { z1v[r] = 0.f; z2v[r] = 0.f; }
    for (int k = 0; k < C; k += 4) {
        float w10 = W1[(size_t)(k + 0) * C + c], w11 = W1[(size_t)(k + 1) * C + c];
        float w12 = W1[(size_t)(k + 2) * C + c], w13 = W1[(size_t)(k + 3) * C + c];
        float w20 = W2[(size_t)(k + 0) * C + c], w21 = W2[(size_t)(k + 1) * C + c];
        float w22 = W2[(size_t)(k + 2) * C + c], w23 = W2[(size_t)(k + 3) * C + c];
#pragma unroll
        for (int r = 0; r < 16; ++r) {
            float4 a = *(const float4*)&sA[rg + r][k];
            float4 b = *(const float4*)&sB[rg + r][k];
            z1v[r] += a.x * w10 + a.y * w11 + a.z * w12 + a.w * w13;
            z2v[r] += b.x * w20 + b.y * w21 + b.z * w22 + b.w * w23;
        }
    }
    const float b1v = b1[c], b2v = b2[c];
#pragma unroll
    for (int r = 0; r < 16; ++r) { z1v[r] += b1v; z2v[r] += b2v; }
    __syncthreads();
#pragma unroll
    for (int r = 0; r < 16; ++r) { sA[rg + r][c] = z1v[r]; sB[rg + r][c] = z2v[r]; }
    __syncthreads();

    float gacc[16];
#pragma unroll
    for (int r = 0; r < 16; ++r) gacc[r] = 0.f;
    for (int k = 0; k < C; k += 4) {
        float g10 = Wg[(size_t)(k + 0) * C + c], g11 = Wg[(size_t)(k + 1) * C + c];
        float g12 = Wg[(size_t)(k + 2) * C + c], g13 = Wg[(size_t)(k + 3) * C + c];
        float g20 = Wg[(size_t)(C + k + 0) * C + c], g21 = Wg[(size_t)(C + k + 1) * C + c];
        float g22 = Wg[(size_t)(C + k + 2) * C + c], g23 = Wg[(size_t)(C + k + 3) * C + c];
#pragma unroll
        for (int r = 0; r < 16; ++r) {
            float4 a = *(const float4*)&sA[rg + r][k];
            float4 b = *(const float4*)&sB[rg + r][k];
            gacc[r] += a.x * g10 + a.y * g11 + a.z * g12 + a.w * g13
                     + b.x * g20 + b.y * g21 + b.z * g22 + b.w * g23;
        }
    }
    const float bgv = bg[c];
#pragma unroll
    for (int r = 0; r < 16; ++r) {
        float g = 1.f / (1.f + expf(-(gacc[r] + bgv)));
        out[(size_t)(r0 + rg + r) * C + c] = g * z1v[r] + (1.f - g) * z2v[r];
    }
}

extern "C" void kernel_launch(void* const* d_in, const int* in_sizes, int n_in,
                              void* d_out, int out_size, void* d_ws, size_t ws_size,
                              hipStream_t stream) {
    const float* x  = (const float*)d_in[0];
    const int*   ei = (const int*)d_in[1];
    const float* W1 = (const float*)d_in[2];
    const float* b1 = (const float*)d_in[3];
    const float* W2 = (const float*)d_in[4];
    const float* b2 = (const float*)d_in[5];
    const float* Wg = (const float*)d_in[6];
    const float* bg = (const float*)d_in[7];
    float* out = (float*)d_out;

    char* ws = (char*)d_ws;
    size_t o = 0;
    auto alloc = [&](size_t bytes) { char* p = ws + o; o = (o + bytes + 255) & ~(size_t)255; return p; };
    int* col      = (int*)alloc((size_t)NEDGE * 4);
    int* deg      = (int*)alloc((size_t)N_NODES * 2 * 4);   // deg + cur contiguous
    int* cur      = deg + N_NODES;
    int* off      = (int*)alloc((size_t)(N_NODES + 1) * 4);
    unsigned* xb  = (unsigned*)alloc((size_t)N_NODES * C * 2);  // bf16 x
    float* agg1   = (float*)alloc((size_t)N_NODES * C * 4);
    float* agg2   = (float*)alloc((size_t)N_NODES * C * 4);

    hipMemsetAsync(deg, 0, (size_t)N_NODES * 2 * 4, stream);

    prep<<<(N_NODES * C / 2 + 255) / 256, 256, 0, stream>>>(x, xb, ei, deg);
    scan_offsets<<<1, 1024, 0, stream>>>(deg, off);
    fill_csr<<<(NEDGE + 255) / 256, 256, 0, stream>>>(ei, off, cur, col);
    twohop_fused<<<N_NODES, 256, 0, stream>>>(off, col, xb, agg1, agg2);
    epilogue<<<N_NODES / 32, 256, 0, stream>>>(agg1, agg2, W1, b1, W2, b2, Wg, bg, out);
}

// Round 5
// 183.567 us; speedup vs baseline: 3.6064x; 1.1461x over previous
//
#include <hip/hip_runtime.h>
#include <math.h>

#define N_NODES 12000
#define C 128
#define NEDGE 192000
#define BW 384  // u32 words per LDS dedup bitset (12288 bits >= 12000)

__device__ __forceinline__ float bflo(unsigned u) { return __uint_as_float(u << 16); }
__device__ __forceinline__ float bfhi(unsigned u) { return __uint_as_float(u & 0xffff0000u); }

#define ACC8(p, u)                                   \
    p##0 += bflo(u.x); p##1 += bfhi(u.x);            \
    p##2 += bflo(u.y); p##3 += bfhi(u.y);            \
    p##4 += bflo(u.z); p##5 += bfhi(u.z);            \
    p##6 += bflo(u.w); p##7 += bfhi(u.w)

#define RED2(x) x += __shfl_xor(x, 16); x += __shfl_xor(x, 32)

// ---- fused: x (fp32) -> bf16 packed pairs  +  out-degree histogram ----
__global__ void prep(const float* __restrict__ x, unsigned* __restrict__ xbu,
                     const int* __restrict__ ei, int* __restrict__ deg) {
    int g = blockIdx.x * blockDim.x + threadIdx.x;
    if (g < N_NODES * C / 2) {
        unsigned a = __float_as_uint(x[2 * g]);
        unsigned b = __float_as_uint(x[2 * g + 1]);
        unsigned ra = (a + 0x7fffu + ((a >> 16) & 1u)) >> 16;
        unsigned rb = (b + 0x7fffu + ((b >> 16) & 1u)) >> 16;
        xbu[g] = ra | (rb << 16);
    }
    if (g < NEDGE) atomicAdd(&deg[ei[g]], 1);
}

// ---- exclusive scan of degrees -> CSR offsets (single 1024-thread block) ----
__global__ __launch_bounds__(1024) void scan_offsets(const int* __restrict__ deg,
                                                     int* __restrict__ off) {
    __shared__ int wsum[16];
    const int t = threadIdx.x;
    const int lane = t & 63, wv = t >> 6;
    const int PER = 12;  // 1024*12 = 12288 >= 12000
    const int lo = t * PER;
    int local[PER];
    int sum = 0;
#pragma unroll
    for (int k = 0; k < PER; ++k) {
        int i = lo + k;
        int d = (i < N_NODES) ? deg[i] : 0;
        local[k] = sum;
        sum += d;
    }
    int p = sum;
    for (int d = 1; d < 64; d <<= 1) {
        int u = __shfl_up(p, d);
        if (lane >= d) p += u;
    }
    if (lane == 63) wsum[wv] = p;
    __syncthreads();
    int wbase = 0;
    for (int k = 0; k < wv; ++k) wbase += wsum[k];
    const int tbase = wbase + p - sum;
#pragma unroll
    for (int k = 0; k < PER; ++k) {
        int i = lo + k;
        if (i < N_NODES) off[i] = tbase + local[k];
    }
    if (t == 0) off[N_NODES] = NEDGE;
}

// ---- fill CSR columns (order within row irrelevant; duplicates kept) ----
__global__ void fill_csr(const int* __restrict__ ei, const int* __restrict__ off,
                         int* __restrict__ cur, int* __restrict__ col) {
    int e = blockIdx.x * blockDim.x + threadIdx.x;
    if (e >= NEDGE) return;
    int s = ei[e];
    int t = ei[NEDGE + e];
    int pos = atomicAdd(&cur[s], 1);
    col[off[s] + pos] = t;
}

// ---- fused: agg1 (bf16 CSR gather) + flattened 2-hop union + list gather ----
__global__ __launch_bounds__(256) void twohop_fused(const int* __restrict__ off,
                                                    const int* __restrict__ col,
                                                    const unsigned* __restrict__ xb,
                                                    float* __restrict__ agg1,
                                                    float* __restrict__ agg2) {
    __shared__ unsigned acc[BW];          // 1.5 KB dedup bitset
    __shared__ int sjb[64];
    __shared__ int spos[64];
    __shared__ int stot;
    __shared__ int wtot[2];
    __shared__ unsigned short lst[4096];  // 8 KB; chunk cap = 128 words * 32 bits
    __shared__ float red[4][256];         // 4 KB
    const int i = blockIdx.x;
    const int tid = threadIdx.x;
    const int lane = tid & 63;
    const int wv = tid >> 6;
    const int grp = tid >> 4, l16 = tid & 15;
    const int rowbeg = off[i], rowend = off[i + 1];
    const uint4* xb4 = (const uint4*)xb;

    for (int w = tid; w < BW; w += 256) acc[w] = 0u;
    __syncthreads();  // acc ready for atomics

    // ---- 2-hop union, flattened per 64-neighbor chunk ----
    for (int base = rowbeg; base < rowend; base += 64) {
        int d = rowend - base;
        if (d > 64) d = 64;
        if (tid < 64) {
            int len = 0;
            if (tid < d) {
                int j = col[base + tid];
                int jb = off[j];
                len = off[j + 1] - jb;
                sjb[tid] = jb;
            }
            int p = len;
            for (int dd = 1; dd < 64; dd <<= 1) {
                int u = __shfl_up(p, dd);
                if (lane >= dd) p += u;
            }
            spos[tid] = p - len;  // exclusive
            if (tid == 63) stot = p;
        }
        __syncthreads();
        const int total = stot;
        for (int q = tid; q < total; q += 256) {
            int lo = 0, hi = d - 1;  // largest k with spos[k] <= q
            while (lo < hi) {
                int mid = (lo + hi + 1) >> 1;
                if (spos[mid] <= q) lo = mid; else hi = mid - 1;
            }
            int t = col[sjb[lo] + (q - spos[lo])];
            atomicOr(&acc[t >> 5], 1u << (t & 31));
        }
        __syncthreads();
    }
    if (tid == 0) acc[i >> 5] &= ~(1u << (i & 31));  // zero diagonal

    // ---- agg1: bf16 counted gather over own row (multiplicity kept), 2x unrolled ----
    float b0 = 0, b1 = 0, b2 = 0, b3 = 0, b4 = 0, b5 = 0, b6 = 0, b7 = 0;
    {
        int idx = rowbeg + grp;
        for (; idx + 16 < rowend; idx += 32) {
            int k0 = col[idx], k1 = col[idx + 16];
            uint4 u0 = xb4[(size_t)k0 * 16 + l16];
            uint4 u1 = xb4[(size_t)k1 * 16 + l16];
            ACC8(b, u0);
            ACC8(b, u1);
        }
        if (idx < rowend) {
            int k0 = col[idx];
            uint4 u0 = xb4[(size_t)k0 * 16 + l16];
            ACC8(b, u0);
        }
    }

    // ---- agg2: per-chunk enumerate (prefix-scan) + counted gather, 2x unrolled ----
    float a0 = 0, a1 = 0, a2 = 0, a3 = 0, a4 = 0, a5 = 0, a6 = 0, a7 = 0;
    for (int chunk = 0; chunk < 3; ++chunk) {
        __syncthreads();  // chunk 0: diag clear visible; others: lst consumed
        unsigned v = 0;
        int n = 0, p = 0;
        if (tid < 128) {
            v = acc[chunk * 128 + tid];
            n = __popc(v);
            p = n;
            for (int dd = 1; dd < 64; dd <<= 1) {
                int u = __shfl_up(p, dd);
                if (lane >= dd) p += u;
            }
            if (lane == 63) wtot[wv] = p;
        }
        __syncthreads();
        if (tid < 128) {
            int o = ((wv == 1) ? wtot[0] : 0) + p - n;
            int wbase = (chunk * 128 + tid) << 5;
            while (v) {
                int b = __ffs(v) - 1;
                v &= v - 1;
                lst[o++] = (unsigned short)(wbase + b);
            }
        }
        __syncthreads();
        const int total = wtot[0] + wtot[1];
        int q = grp;
        for (; q + 16 < total; q += 32) {
            int k0 = lst[q], k1 = lst[q + 16];
            uint4 u0 = xb4[(size_t)k0 * 16 + l16];
            uint4 u1 = xb4[(size_t)k1 * 16 + l16];
            ACC8(a, u0);
            ACC8(a, u1);
        }
        if (q < total) {
            int k0 = lst[q];
            uint4 u0 = xb4[(size_t)k0 * 16 + l16];
            ACC8(a, u0);
        }
    }

    // ---- cross-group reduction: shuffle within wave, then 4-wave LDS combine ----
    RED2(a0); RED2(a1); RED2(a2); RED2(a3); RED2(a4); RED2(a5); RED2(a6); RED2(a7);
    RED2(b0); RED2(b1); RED2(b2); RED2(b3); RED2(b4); RED2(b5); RED2(b6); RED2(b7);
    __syncthreads();  // lst fully consumed (not strictly needed, red is separate)
    if (lane < 16) {
        red[wv][l16 * 8 + 0] = a0; red[wv][l16 * 8 + 1] = a1;
        red[wv][l16 * 8 + 2] = a2; red[wv][l16 * 8 + 3] = a3;
        red[wv][l16 * 8 + 4] = a4; red[wv][l16 * 8 + 5] = a5;
        red[wv][l16 * 8 + 6] = a6; red[wv][l16 * 8 + 7] = a7;
        red[wv][128 + l16 * 8 + 0] = b0; red[wv][128 + l16 * 8 + 1] = b1;
        red[wv][128 + l16 * 8 + 2] = b2; red[wv][128 + l16 * 8 + 3] = b3;
        red[wv][128 + l16 * 8 + 4] = b4; red[wv][128 + l16 * 8 + 5] = b5;
        red[wv][128 + l16 * 8 + 6] = b6; red[wv][128 + l16 * 8 + 7] = b7;
    }
    __syncthreads();
    float s = red[0][tid] + red[1][tid] + red[2][tid] + red[3][tid];
    if (tid < 128) agg2[(size_t)i * C + tid] = s;
    else           agg1[(size_t)i * C + (tid - 128)] = s;
}

// ---- fused epilogue: z1 = agg1@W1+b1, z2 = agg2@W2+b2, gate, combine ----
__global__ __launch_bounds__(256) void epilogue(const float* __restrict__ agg1,
                                                const float* __restrict__ agg2,
                                                const float* __restrict__ W1,
                                                const float* __restrict__ b1,
                                                const float* __restrict__ W2,
                                                const float* __restrict__ b2,
                                                const float* __restrict__ Wg,
                                                const float* __restrict__ bg,
                                                float* __restrict__ out) {
    __shared__ float sA[32][C];  // agg1 tile, then z1 tile
    __shared__ float sB[32][C];  // agg2 tile, then z2 tile
    const int r0 = blockIdx.x * 32;
    const int tid = threadIdx.x;
    const int c = tid & 127;
    const int rg = (tid >> 7) * 16;

    for (int idx = tid; idx < 32 * C; idx += 256) {
        int r = idx >> 7, k = idx & 127;
        sA[r][k] = agg1[(size_t)(r0 + r) * C + k];
        sB[r][k] = agg2[(size_t)(r0 + r) * C + k];
    }
    __syncthreads();

    float z1v[16], z2v[16];
#pragma unroll
    for (int r = 0; r < 16; ++r) { z1v[r] = 0.f; z2v[r] = 0.f; }
    for (int k = 0; k < C; k += 4) {
        float w10 = W1[(size_t)(k + 0) * C + c], w11 = W1[(size_t)(k + 1) * C + c];
        float w12 = W1[(size_t)(k + 2) * C + c], w13 = W1[(size_t)(k + 3) * C + c];
        float w20 = W2[(size_t)(k + 0) * C + c], w21 = W2[(size_t)(k + 1) * C + c];
        float w22 = W2[(size_t)(k + 2) * C + c], w23 = W2[(size_t)(k + 3) * C + c];
#pragma unroll
        for (int r = 0; r < 16; ++r) {
            float4 a = *(const float4*)&sA[rg + r][k];
            float4 b = *(const float4*)&sB[rg + r][k];
            z1v[r] += a.x * w10 + a.y * w11 + a.z * w12 + a.w * w13;
            z2v[r] += b.x * w20 + b.y * w21 + b.z * w22 + b.w * w23;
        }
    }
    const float b1v = b1[c], b2v = b2[c];
#pragma unroll
    for (int r = 0; r < 16; ++r) { z1v[r] += b1v; z2v[r] += b2v; }
    __syncthreads();
#pragma unroll
    for (int r = 0; r < 16; ++r) { sA[rg + r][c] = z1v[r]; sB[rg + r][c] = z2v[r]; }
    __syncthreads();

    float gacc[16];
#pragma unroll
    for (int r = 0; r < 16; ++r) gacc[r] = 0.f;
    for (int k = 0; k < C; k += 4) {
        float g10 = Wg[(size_t)(k + 0) * C + c], g11 = Wg[(size_t)(k + 1) * C + c];
        float g12 = Wg[(size_t)(k + 2) * C + c], g13 = Wg[(size_t)(k + 3) * C + c];
        float g20 = Wg[(size_t)(C + k + 0) * C + c], g21 = Wg[(size_t)(C + k + 1) * C + c];
        float g22 = Wg[(size_t)(C + k + 2) * C + c], g23 = Wg[(size_t)(C + k + 3) * C + c];
#pragma unroll
        for (int r = 0; r < 16; ++r) {
            float4 a = *(const float4*)&sA[rg + r][k];
            float4 b = *(const float4*)&sB[rg + r][k];
            gacc[r] += a.x * g10 + a.y * g11 + a.z * g12 + a.w * g13
                     + b.x * g20 + b.y * g21 + b.z * g22 + b.w * g23;
        }
    }
    const float bgv = bg[c];
#pragma unroll
    for (int r = 0; r < 16; ++r) {
        float g = 1.f / (1.f + expf(-(gacc[r] + bgv)));
        out[(size_t)(r0 + rg + r) * C + c] = g * z1v[r] + (1.f - g) * z2v[r];
    }
}

extern "C" void kernel_launch(void* const* d_in, const int* in_sizes, int n_in,
                              void* d_out, int out_size, void* d_ws, size_t ws_size,
                              hipStream_t stream) {
    const float* x  = (const float*)d_in[0];
    const int*   ei = (const int*)d_in[1];
    const float* W1 = (const float*)d_in[2];
    const float* b1 = (const float*)d_in[3];
    const float* W2 = (const float*)d_in[4];
    const float* b2 = (const float*)d_in[5];
    const float* Wg = (const float*)d_in[6];
    const float* bg = (const float*)d_in[7];
    float* out = (float*)d_out;

    char* ws = (char*)d_ws;
    size_t o = 0;
    auto alloc = [&](size_t bytes) { char* p = ws + o; o = (o + bytes + 255) & ~(size_t)255; return p; };
    int* col      = (int*)alloc((size_t)NEDGE * 4);
    int* deg      = (int*)alloc((size_t)N_NODES * 2 * 4);   // deg + cur contiguous
    int* cur      = deg + N_NODES;
    int* off      = (int*)alloc((size_t)(N_NODES + 1) * 4);
    unsigned* xb  = (unsigned*)alloc((size_t)N_NODES * C * 2);  // bf16 x
    float* agg1   = (float*)alloc((size_t)N_NODES * C * 4);
    float* agg2   = (float*)alloc((size_t)N_NODES * C * 4);

    hipMemsetAsync(deg, 0, (size_t)N_NODES * 2 * 4, stream);

    prep<<<(N_NODES * C / 2 + 255) / 256, 256, 0, stream>>>(x, xb, ei, deg);
    scan_offsets<<<1, 1024, 0, stream>>>(deg, off);
    fill_csr<<<(NEDGE + 255) / 256, 256, 0, stream>>>(ei, off, cur, col);
    twohop_fused<<<N_NODES, 256, 0, stream>>>(off, col, xb, agg1, agg2);
    epilogue<<<N_NODES / 32, 256, 0, stream>>>(agg1, agg2, W1, b1, W2, b2, Wg, bg, out);
}

// Round 6
// 161.292 us; speedup vs baseline: 4.1044x; 1.1381x over previous
//
#include <hip/hip_runtime.h>
#include <math.h>

#define N_NODES 12000
#define C 128
#define NEDGE 192000
#define BW 384  // u32 words per LDS dedup bitset (12288 bits >= 12000)

__device__ __forceinline__ float bflo(unsigned u) { return __uint_as_float(u << 16); }
__device__ __forceinline__ float bfhi(unsigned u) { return __uint_as_float(u & 0xffff0000u); }

#define ACC8(p, u)                                   \
    p##0 += bflo(u.x); p##1 += bfhi(u.x);            \
    p##2 += bflo(u.y); p##3 += bfhi(u.y);            \
    p##4 += bflo(u.z); p##5 += bfhi(u.z);            \
    p##6 += bflo(u.w); p##7 += bfhi(u.w)

#define RED2(x) x += __shfl_xor(x, 16); x += __shfl_xor(x, 32)

// ---- fused: x (fp32) -> bf16 packed pairs  +  out-degree histogram ----
__global__ void prep(const float* __restrict__ x, unsigned* __restrict__ xbu,
                     const int* __restrict__ ei, int* __restrict__ deg) {
    int g = blockIdx.x * blockDim.x + threadIdx.x;
    if (g < N_NODES * C / 2) {
        unsigned a = __float_as_uint(x[2 * g]);
        unsigned b = __float_as_uint(x[2 * g + 1]);
        unsigned ra = (a + 0x7fffu + ((a >> 16) & 1u)) >> 16;
        unsigned rb = (b + 0x7fffu + ((b >> 16) & 1u)) >> 16;
        xbu[g] = ra | (rb << 16);
    }
    if (g < NEDGE) atomicAdd(&deg[ei[g]], 1);
}

// ---- exclusive scan of degrees -> CSR offsets (single 1024-thread block) ----
__global__ __launch_bounds__(1024) void scan_offsets(const int* __restrict__ deg,
                                                     int* __restrict__ off) {
    __shared__ int wsum[16];
    const int t = threadIdx.x;
    const int lane = t & 63, wv = t >> 6;
    const int PER = 12;  // 1024*12 = 12288 >= 12000
    const int lo = t * PER;
    int local[PER];
    int sum = 0;
#pragma unroll
    for (int k = 0; k < PER; ++k) {
        int i = lo + k;
        int d = (i < N_NODES) ? deg[i] : 0;
        local[k] = sum;
        sum += d;
    }
    int p = sum;
    for (int d = 1; d < 64; d <<= 1) {
        int u = __shfl_up(p, d);
        if (lane >= d) p += u;
    }
    if (lane == 63) wsum[wv] = p;
    __syncthreads();
    int wbase = 0;
    for (int k = 0; k < wv; ++k) wbase += wsum[k];
    const int tbase = wbase + p - sum;
#pragma unroll
    for (int k = 0; k < PER; ++k) {
        int i = lo + k;
        if (i < N_NODES) off[i] = tbase + local[k];
    }
    if (t == 0) off[N_NODES] = NEDGE;
}

// ---- fill CSR columns (order within row irrelevant; duplicates kept) ----
__global__ void fill_csr(const int* __restrict__ ei, const int* __restrict__ off,
                         int* __restrict__ cur, int* __restrict__ col) {
    int e = blockIdx.x * blockDim.x + threadIdx.x;
    if (e >= NEDGE) return;
    int s = ei[e];
    int t = ei[NEDGE + e];
    int pos = atomicAdd(&cur[s], 1);
    col[off[s] + pos] = t;
}

// ---- fused: agg1 (bf16 CSR gather) + flattened 2-hop union + list gather ----
__global__ __launch_bounds__(256) void twohop_fused(const int* __restrict__ off,
                                                    const int* __restrict__ col,
                                                    const unsigned* __restrict__ xb,
                                                    float* __restrict__ agg1,
                                                    float* __restrict__ agg2) {
    __shared__ unsigned acc[BW];          // 1.5 KB dedup bitset
    __shared__ int sjb[64];
    __shared__ int spos[64];
    __shared__ int stot;
    __shared__ int wtot[2];
    __shared__ unsigned short lst[4096];  // 8 KB; chunk cap = 128 words * 32 bits
    __shared__ float red[4][256];         // 4 KB
    const int i = blockIdx.x;
    const int tid = threadIdx.x;
    const int lane = tid & 63;
    const int wv = tid >> 6;
    const int grp = tid >> 4, l16 = tid & 15;
    const int rowbeg = off[i], rowend = off[i + 1];
    const uint4* xb4 = (const uint4*)xb;

    for (int w = tid; w < BW; w += 256) acc[w] = 0u;
    __syncthreads();  // acc ready for atomics

    // ---- 2-hop union, flattened per 64-neighbor chunk ----
    for (int base = rowbeg; base < rowend; base += 64) {
        int d = rowend - base;
        if (d > 64) d = 64;
        if (tid < 64) {
            int len = 0;
            if (tid < d) {
                int j = col[base + tid];
                int jb = off[j];
                len = off[j + 1] - jb;
                sjb[tid] = jb;
            }
            int p = len;
            for (int dd = 1; dd < 64; dd <<= 1) {
                int u = __shfl_up(p, dd);
                if (lane >= dd) p += u;
            }
            spos[tid] = p - len;  // exclusive
            if (tid == 63) stot = p;
        }
        __syncthreads();
        const int total = stot;
        for (int q = tid; q < total; q += 256) {
            int lo = 0, hi = d - 1;  // largest k with spos[k] <= q
            while (lo < hi) {
                int mid = (lo + hi + 1) >> 1;
                if (spos[mid] <= q) lo = mid; else hi = mid - 1;
            }
            int t = col[sjb[lo] + (q - spos[lo])];
            atomicOr(&acc[t >> 5], 1u << (t & 31));
        }
        __syncthreads();
    }
    if (tid == 0) acc[i >> 5] &= ~(1u << (i & 31));  // zero diagonal

    // ---- agg1: bf16 counted gather over own row (multiplicity kept), 2x unrolled ----
    float b0 = 0, b1 = 0, b2 = 0, b3 = 0, b4 = 0, b5 = 0, b6 = 0, b7 = 0;
    {
        int idx = rowbeg + grp;
        for (; idx + 16 < rowend; idx += 32) {
            int k0 = col[idx], k1 = col[idx + 16];
            uint4 u0 = xb4[(size_t)k0 * 16 + l16];
            uint4 u1 = xb4[(size_t)k1 * 16 + l16];
            ACC8(b, u0);
            ACC8(b, u1);
        }
        if (idx < rowend) {
            int k0 = col[idx];
            uint4 u0 = xb4[(size_t)k0 * 16 + l16];
            ACC8(b, u0);
        }
    }

    // ---- agg2: per-chunk enumerate (prefix-scan) + counted gather, 4x unrolled ----
    float a0 = 0, a1 = 0, a2 = 0, a3 = 0, a4 = 0, a5 = 0, a6 = 0, a7 = 0;
    for (int chunk = 0; chunk < 3; ++chunk) {
        __syncthreads();  // chunk 0: diag clear visible; others: lst consumed
        unsigned v = 0;
        int n = 0, p = 0;
        if (tid < 128) {
            v = acc[chunk * 128 + tid];
            n = __popc(v);
            p = n;
            for (int dd = 1; dd < 64; dd <<= 1) {
                int u = __shfl_up(p, dd);
                if (lane >= dd) p += u;
            }
            if (lane == 63) wtot[wv] = p;
        }
        __syncthreads();
        if (tid < 128) {
            int o = ((wv == 1) ? wtot[0] : 0) + p - n;
            int wbase = (chunk * 128 + tid) << 5;
            while (v) {
                int b = __ffs(v) - 1;
                v &= v - 1;
                lst[o++] = (unsigned short)(wbase + b);
            }
        }
        __syncthreads();
        const int total = wtot[0] + wtot[1];
        int q = grp;
        for (; q + 48 < total; q += 64) {
            int k0 = lst[q], k1 = lst[q + 16], k2 = lst[q + 32], k3 = lst[q + 48];
            uint4 u0 = xb4[(size_t)k0 * 16 + l16];
            uint4 u1 = xb4[(size_t)k1 * 16 + l16];
            uint4 u2 = xb4[(size_t)k2 * 16 + l16];
            uint4 u3 = xb4[(size_t)k3 * 16 + l16];
            ACC8(a, u0);
            ACC8(a, u1);
            ACC8(a, u2);
            ACC8(a, u3);
        }
        for (; q + 16 < total; q += 32) {
            int k0 = lst[q], k1 = lst[q + 16];
            uint4 u0 = xb4[(size_t)k0 * 16 + l16];
            uint4 u1 = xb4[(size_t)k1 * 16 + l16];
            ACC8(a, u0);
            ACC8(a, u1);
        }
        if (q < total) {
            int k0 = lst[q];
            uint4 u0 = xb4[(size_t)k0 * 16 + l16];
            ACC8(a, u0);
        }
    }

    // ---- cross-group reduction: shuffle within wave, then 4-wave LDS combine ----
    RED2(a0); RED2(a1); RED2(a2); RED2(a3); RED2(a4); RED2(a5); RED2(a6); RED2(a7);
    RED2(b0); RED2(b1); RED2(b2); RED2(b3); RED2(b4); RED2(b5); RED2(b6); RED2(b7);
    __syncthreads();
    if (lane < 16) {
        red[wv][l16 * 8 + 0] = a0; red[wv][l16 * 8 + 1] = a1;
        red[wv][l16 * 8 + 2] = a2; red[wv][l16 * 8 + 3] = a3;
        red[wv][l16 * 8 + 4] = a4; red[wv][l16 * 8 + 5] = a5;
        red[wv][l16 * 8 + 6] = a6; red[wv][l16 * 8 + 7] = a7;
        red[wv][128 + l16 * 8 + 0] = b0; red[wv][128 + l16 * 8 + 1] = b1;
        red[wv][128 + l16 * 8 + 2] = b2; red[wv][128 + l16 * 8 + 3] = b3;
        red[wv][128 + l16 * 8 + 4] = b4; red[wv][128 + l16 * 8 + 5] = b5;
        red[wv][128 + l16 * 8 + 6] = b6; red[wv][128 + l16 * 8 + 7] = b7;
    }
    __syncthreads();
    float s = red[0][tid] + red[1][tid] + red[2][tid] + red[3][tid];
    if (tid < 128) agg2[(size_t)i * C + tid] = s;
    else           agg1[(size_t)i * C + (tid - 128)] = s;
}

// ---- fused epilogue: z1 = agg1@W1+b1, z2 = agg2@W2+b2, gate, combine ----
// 8 rows/block -> 1500 blocks (~5.9/CU) for occupancy; each thread 4 rows.
__global__ __launch_bounds__(256) void epilogue(const float* __restrict__ agg1,
                                                const float* __restrict__ agg2,
                                                const float* __restrict__ W1,
                                                const float* __restrict__ b1,
                                                const float* __restrict__ W2,
                                                const float* __restrict__ b2,
                                                const float* __restrict__ Wg,
                                                const float* __restrict__ bg,
                                                float* __restrict__ out) {
    __shared__ float sA[8][C];  // agg1 tile, then z1 tile
    __shared__ float sB[8][C];  // agg2 tile, then z2 tile
    const int r0 = blockIdx.x * 8;
    const int tid = threadIdx.x;
    const int c = tid & 127;
    const int rg = (tid >> 7) * 4;

    for (int idx = tid; idx < 8 * C; idx += 256) {
        int r = idx >> 7, k = idx & 127;
        sA[r][k] = agg1[(size_t)(r0 + r) * C + k];
        sB[r][k] = agg2[(size_t)(r0 + r) * C + k];
    }
    __syncthreads();

    float z1v[4], z2v[4];
#pragma unroll
    for (int r = 0; r < 4; ++r) { z1v[r] = 0.f; z2v[r] = 0.f; }
    for (int k = 0; k < C; k += 4) {
        float w10 = W1[(size_t)(k + 0) * C + c], w11 = W1[(size_t)(k + 1) * C + c];
        float w12 = W1[(size_t)(k + 2) * C + c], w13 = W1[(size_t)(k + 3) * C + c];
        float w20 = W2[(size_t)(k + 0) * C + c], w21 = W2[(size_t)(k + 1) * C + c];
        float w22 = W2[(size_t)(k + 2) * C + c], w23 = W2[(size_t)(k + 3) * C + c];
#pragma unroll
        for (int r = 0; r < 4; ++r) {
            float4 a = *(const float4*)&sA[rg + r][k];
            float4 b = *(const float4*)&sB[rg + r][k];
            z1v[r] += a.x * w10 + a.y * w11 + a.z * w12 + a.w * w13;
            z2v[r] += b.x * w20 + b.y * w21 + b.z * w22 + b.w * w23;
        }
    }
    const float b1v = b1[c], b2v = b2[c];
#pragma unroll
    for (int r = 0; r < 4; ++r) { z1v[r] += b1v; z2v[r] += b2v; }
    __syncthreads();
#pragma unroll
    for (int r = 0; r < 4; ++r) { sA[rg + r][c] = z1v[r]; sB[rg + r][c] = z2v[r]; }
    __syncthreads();

    float gacc[4];
#pragma unroll
    for (int r = 0; r < 4; ++r) gacc[r] = 0.f;
    for (int k = 0; k < C; k += 4) {
        float g10 = Wg[(size_t)(k + 0) * C + c], g11 = Wg[(size_t)(k + 1) * C + c];
        float g12 = Wg[(size_t)(k + 2) * C + c], g13 = Wg[(size_t)(k + 3) * C + c];
        float g20 = Wg[(size_t)(C + k + 0) * C + c], g21 = Wg[(size_t)(C + k + 1) * C + c];
        float g22 = Wg[(size_t)(C + k + 2) * C + c], g23 = Wg[(size_t)(C + k + 3) * C + c];
#pragma unroll
        for (int r = 0; r < 4; ++r) {
            float4 a = *(const float4*)&sA[rg + r][k];
            float4 b = *(const float4*)&sB[rg + r][k];
            gacc[r] += a.x * g10 + a.y * g11 + a.z * g12 + a.w * g13
                     + b.x * g20 + b.y * g21 + b.z * g22 + b.w * g23;
        }
    }
    const float bgv = bg[c];
#pragma unroll
    for (int r = 0; r < 4; ++r) {
        float g = 1.f / (1.f + expf(-(gacc[r] + bgv)));
        out[(size_t)(r0 + rg + r) * C + c] = g * z1v[r] + (1.f - g) * z2v[r];
    }
}

extern "C" void kernel_launch(void* const* d_in, const int* in_sizes, int n_in,
                              void* d_out, int out_size, void* d_ws, size_t ws_size,
                              hipStream_t stream) {
    const float* x  = (const float*)d_in[0];
    const int*   ei = (const int*)d_in[1];
    const float* W1 = (const float*)d_in[2];
    const float* b1 = (const float*)d_in[3];
    const float* W2 = (const float*)d_in[4];
    const float* b2 = (const float*)d_in[5];
    const float* Wg = (const float*)d_in[6];
    const float* bg = (const float*)d_in[7];
    float* out = (float*)d_out;

    char* ws = (char*)d_ws;
    size_t o = 0;
    auto alloc = [&](size_t bytes) { char* p = ws + o; o = (o + bytes + 255) & ~(size_t)255; return p; };
    int* col      = (int*)alloc((size_t)NEDGE * 4);
    int* deg      = (int*)alloc((size_t)N_NODES * 2 * 4);   // deg + cur contiguous
    int* cur      = deg + N_NODES;
    int* off      = (int*)alloc((size_t)(N_NODES + 1) * 4);
    unsigned* xb  = (unsigned*)alloc((size_t)N_NODES * C * 2);  // bf16 x
    float* agg1   = (float*)alloc((size_t)N_NODES * C * 4);
    float* agg2   = (float*)alloc((size_t)N_NODES * C * 4);

    hipMemsetAsync(deg, 0, (size_t)N_NODES * 2 * 4, stream);

    prep<<<(N_NODES * C / 2 + 255) / 256, 256, 0, stream>>>(x, xb, ei, deg);
    scan_offsets<<<1, 1024, 0, stream>>>(deg, off);
    fill_csr<<<(NEDGE + 255) / 256, 256, 0, stream>>>(ei, off, cur, col);
    twohop_fused<<<N_NODES, 256, 0, stream>>>(off, col, xb, agg1, agg2);
    epilogue<<<N_NODES / 8, 256, 0, stream>>>(agg1, agg2, W1, b1, W2, b2, Wg, bg, out);
}